// Round 4
// baseline (481.086 us; speedup 1.0000x reference)
//
#include <hip/hip_runtime.h>
#include <math.h>

#define N_ROWS 16384
#define DMODEL 1024
#define DFF    4096

typedef _Float16 f16;
typedef __attribute__((ext_vector_type(4))) _Float16 f16x4;
typedef __attribute__((ext_vector_type(8))) _Float16 f16x8;
typedef __attribute__((ext_vector_type(4))) float f32x4;
typedef __attribute__((ext_vector_type(16))) float f32x16;

__device__ inline void async_ld16(const f16* g, f16* l) {
  __builtin_amdgcn_global_load_lds(
      (__attribute__((address_space(1))) void*)(g),
      (__attribute__((address_space(3))) void*)(l),
      16, 0, 0);
}

// tanh via hw v_exp_f32 (~5 VALU ops, saturates correctly at +-inf)
__device__ inline float fast_tanh(float x) {
  float t = __expf(2.0f * x);
  return 1.0f - 2.0f / (t + 1.0f);
}

// One kernel casts all three fp32 inputs to f16 (saves 2 launches).
__global__ void cast3_to_f16(const float* __restrict__ a, f16* __restrict__ ah, int na,
                             const float* __restrict__ b, f16* __restrict__ bh, int nb,
                             const float* __restrict__ c, f16* __restrict__ ch, int nc) {
  long i = (long)(blockIdx.x * blockDim.x + threadIdx.x) * 8;
  const float* s; f16* d;
  if (i < na)                { s = a + i;            d = ah + i; }
  else if (i < na + nb)      { s = b + (i - na);     d = bh + (i - na); }
  else if (i < na + nb + nc) { s = c + (i - na - nb); d = ch + (i - na - nb); }
  else return;
  float4 v0 = ((const float4*)s)[0];
  float4 v1 = ((const float4*)s)[1];
  f16x8 h = { (f16)v0.x, (f16)v0.y, (f16)v0.z, (f16)v0.w,
              (f16)v1.x, (f16)v1.y, (f16)v1.z, (f16)v1.w };
  *(f16x8*)d = h;
}

// C[M,Nc] = tanh(A[M,K] @ B[Nc,K]^T + bias) -> f16, fp32 acc.
// 128x128 block tile, BK=64 staged as two [128][32] half-tiles (as round 3).
// NEW: 32x32x16 MFMA, 2x2 frags per wave (same 64x64 wave tile, same LDS
// bytes, same 64 acc VGPRs) -> half the MFMA instructions at a 15% higher
// ceiling (2382 vs 2075 TF, m06), 4 independent MFMAs per k-step.
// A/B frag map: m|n = lane&31, k = (lane>>5)*8 + j  (32x32 analog of the
// verified 16x16x32 map). C/D: col=lane&31, row=(reg&3)+8*(reg>>2)+4*(lane>>5)
// [m74/m101-verified].
template <int K>
__global__ __launch_bounds__(256, 3)
void gemm_bt_tanh(const f16* __restrict__ A, const f16* __restrict__ B,
                  const float* __restrict__ bias, f16* __restrict__ C, int Nc) {
  __shared__ __align__(16) f16 As[2 * 128 * 32];
  __shared__ __align__(16) f16 Bs[2 * 128 * 32];

  const int tid  = threadIdx.x;
  const int lane = tid & 63;
  const int wave = tid >> 6;
  const size_t row0 = (size_t)blockIdx.x * 128;
  const size_t col0 = (size_t)blockIdx.y * 128;
  const int wm = (wave >> 1) * 64;
  const int wn = (wave & 1) * 64;
  const int lr = lane & 31;        // row/col within a 32-tile
  const int lk = (lane >> 5) * 8;  // k-offset base within a 16-k step

  // Staging (identical to round 3): 4 16B loads per operand per thread.
  // Load l covers half-tile h=l>>1 (k 0..31 vs 32..63); slot sp=(l&1)*256+tid;
  // row = sp>>2, k-chunk = h*4 + (sp&3). LDS dest = half-base + sp*16B.
  const f16* Ag[4]; const f16* Bg[4]; f16* Asd[4]; f16* Bsd[4];
#pragma unroll
  for (int l = 0; l < 4; ++l) {
    const int sp  = (l & 1) * 256 + tid;
    const int row = sp >> 2;
    const int kch = (l >> 1) * 4 + (sp & 3);
    Ag[l]  = A + (row0 + row) * (size_t)K + kch * 8;
    Bg[l]  = B + (col0 + row) * (size_t)K + kch * 8;
    Asd[l] = As + (l >> 1) * 4096 + sp * 8;
    Bsd[l] = Bs + (l >> 1) * 4096 + sp * 8;
  }

  f32x16 acc[2][2] = {};

  for (int k0 = 0; k0 < K; k0 += 64) {
    __syncthreads();
#pragma unroll
    for (int l = 0; l < 4; ++l) async_ld16(Ag[l] + k0, Asd[l]);
#pragma unroll
    for (int l = 0; l < 4; ++l) async_ld16(Bg[l] + k0, Bsd[l]);
    __syncthreads();

#pragma unroll
    for (int s = 0; s < 2; ++s) {      // LDS half-tile (k 0..31 / 32..63)
#pragma unroll
      for (int t = 0; t < 2; ++t) {    // 16-k step within half
        f16x8 af[2], bf[2];
#pragma unroll
        for (int i = 0; i < 2; ++i) {
          af[i] = *(const f16x8*)(As + s * 4096 + (wm + i * 32 + lr) * 32 + t * 16 + lk);
          bf[i] = *(const f16x8*)(Bs + s * 4096 + (wn + i * 32 + lr) * 32 + t * 16 + lk);
        }
#pragma unroll
        for (int i = 0; i < 2; ++i)
#pragma unroll
          for (int j = 0; j < 2; ++j)
            acc[i][j] = __builtin_amdgcn_mfma_f32_32x32x16_f16(af[i], bf[j], acc[i][j], 0, 0, 0);
      }
    }
  }

  // Epilogue. D map: col=lane&31, row=(reg&3)+8*(reg>>2)+4*(lane>>5).
  const int rbase = 4 * (lane >> 5);
#pragma unroll
  for (int i = 0; i < 2; ++i) {
#pragma unroll
    for (int j = 0; j < 2; ++j) {
      size_t gcol = col0 + wn + j * 32 + lr;
      float b = bias[gcol];
#pragma unroll
      for (int reg = 0; reg < 16; ++reg) {
        int r = (reg & 3) + 8 * (reg >> 2) + rbase;
        size_t grow = row0 + wm + i * 32 + r;
        C[grow * (size_t)Nc + gcol] = (f16)fast_tanh(acc[i][j][reg] + b);
      }
    }
  }
}

// out[row] = sigmoid(sum_k wx[row][k] * batch[row][k]); 256 thr/row, fp32 acc
__global__ void rowdot_sigmoid(const f16* __restrict__ wx, const float* __restrict__ batch,
                               float* __restrict__ out) {
  const int row = blockIdx.x;
  const int t = threadIdx.x;
  const f16* wr = wx + (size_t)row * DMODEL + t * 4;
  const float* br = batch + (size_t)row * DMODEL + t * 4;
  f16x4 h = *(const f16x4*)wr;
  float4 b4 = *(const float4*)br;
  float s = (float)h[0] * b4.x + (float)h[1] * b4.y + (float)h[2] * b4.z + (float)h[3] * b4.w;
#pragma unroll
  for (int off = 32; off > 0; off >>= 1) s += __shfl_down(s, off, 64);
  __shared__ float partial[4];
  if ((t & 63) == 0) partial[t >> 6] = s;
  __syncthreads();
  if (t == 0) {
    float tot = partial[0] + partial[1] + partial[2] + partial[3];
    out[row] = 1.0f / (1.0f + __expf(-tot));
  }
}

extern "C" void kernel_launch(void* const* d_in, const int* in_sizes, int n_in,
                              void* d_out, int out_size, void* d_ws, size_t ws_size,
                              hipStream_t stream) {
  const float* batch = (const float*)d_in[0];
  const float* W1    = (const float*)d_in[1];
  const float* b1    = (const float*)d_in[2];
  const float* W2    = (const float*)d_in[3];
  const float* b2    = (const float*)d_in[4];
  float* out = (float*)d_out;

  char* ws = (char*)d_ws;
  f16* batch_h = (f16*)ws;  ws += (size_t)N_ROWS * DMODEL * sizeof(f16);  //  32 MB
  f16* W1_h    = (f16*)ws;  ws += (size_t)DFF * DMODEL * sizeof(f16);     //   8 MB
  f16* W2_h    = (f16*)ws;  ws += (size_t)DMODEL * DFF * sizeof(f16);     //   8 MB
  f16* inner_h = (f16*)ws;  ws += (size_t)N_ROWS * DFF * sizeof(f16);     // 128 MB
  f16* wx_h    = (f16*)ws;  ws += (size_t)N_ROWS * DMODEL * sizeof(f16);  //  32 MB

  const int nb = N_ROWS * DMODEL;   // 16.7M
  const int nw = DFF * DMODEL;      //  4.2M
  const int total8 = (nb + nw + nw) / 8;  // 3,145,728 threads
  cast3_to_f16<<<total8 / 256, 256, 0, stream>>>(batch, batch_h, nb,
                                                 W1, W1_h, nw, W2, W2_h, nw);

  dim3 g1(N_ROWS / 128, DFF / 128);     // (128, 32)
  gemm_bt_tanh<DMODEL><<<g1, 256, 0, stream>>>(batch_h, W1_h, b1, inner_h, DFF);
  dim3 g2(N_ROWS / 128, DMODEL / 128);  // (128, 8)
  gemm_bt_tanh<DFF><<<g2, 256, 0, stream>>>(inner_h, W2_h, b2, wx_h, DMODEL);

  rowdot_sigmoid<<<N_ROWS, 256, 0, stream>>>(wx_h, batch, out);
}